// Round 4
// baseline (219.345 us; speedup 1.0000x reference)
//
#include <hip/hip_runtime.h>

// Problem constants: (B, C, H, W) = (32, 3, 512, 512), fp32.
#define HW_PLANE (512 * 512)          // 262144 floats per channel plane
#define NPIX     (32 * HW_PLANE)      // 8,388,608 pixels
#define NBLOCKS  2048
#define WAVE_PX  256                  // pixels per wave per subtile (1 KB/plane)
#define SUBTILES 4                    // per block -> block covers 4*4*256 = 4096 px
#define BLOCK_PX (4 * WAVE_PX * SUBTILES)

typedef __attribute__((address_space(3))) float*       lds_fp;
typedef const __attribute__((address_space(1))) float* glb_fp;

// Async global->LDS DMA, 16 B/lane (1 KB per wave-instruction), no VGPR dest.
__device__ __forceinline__ void stage16(const float* g, float* l) {
    __builtin_amdgcn_global_load_lds((glb_fp)g, (lds_fp)l, 16, 0, 0);
}

__device__ __forceinline__ float hue1(float r, float g, float b) {
    float maxc  = fmaxf(r, fmaxf(g, b));
    float minc  = fminf(r, fminf(g, b));
    float delta = maxc - minc;
    float safe  = (delta == 0.0f) ? 1.0f : delta;
    float rs    = __builtin_amdgcn_rcpf(safe);
    float hr = (g - b) * rs;
    float hg = 2.0f + (b - r) * rs;
    float hb = 4.0f + (r - g) * rs;
    float h  = (maxc == r) ? hr : ((maxc == g) ? hg : hb);
    h = h * (1.0f / 6.0f);
    h = h - floorf(h);                 // Python % 1.0
    return (delta == 0.0f) ? 0.0f : h;
}

__device__ __forceinline__ void acc_diff(float hp, float ht, float& lo, float& hi) {
    float d = fabsf(hp - ht);
    if (d < 0.5f)      lo += d;        // d == 0.5 contributes to neither term
    else if (d > 0.5f) hi += d - 0.5f;
}

__global__ void __launch_bounds__(256)
hsv_partial(const float* __restrict__ pred, const float* __restrict__ targ,
            float2* __restrict__ partial) {
    // Wave-private double-buffered tiles: [wave][buf][plane][256 px] = 48 KB.
    __shared__ float lds[4 * 2 * 6 * WAVE_PX];

    const int lane = threadIdx.x & 63;
    const int wave = threadIdx.x >> 6;
    const int blockpix = blockIdx.x * BLOCK_PX;        // 4096-aligned -> one image
    const int img  = blockpix >> 18;                   // / HW_PLANE
    const int pix0 = (blockpix & (HW_PLANE - 1)) + wave * WAVE_PX;
    const float* pbase = pred + img * (3 * HW_PLANE) + pix0;
    const float* tbase = targ + img * (3 * HW_PLANE) + pix0;

    float* lbuf[2] = { &lds[(wave * 2 + 0) * 6 * WAVE_PX],
                       &lds[(wave * 2 + 1) * 6 * WAVE_PX] };

    // Stage subtile s into LDS buffer lb: 6 fire-and-forget 1 KB DMAs.
    auto stage = [&](int s, float* lb) {
        const int off = s * (4 * WAVE_PX) + lane * 4;  // subtile stride = 1024 px
        #pragma unroll
        for (int c = 0; c < 3; ++c) {
            stage16(pbase + c * HW_PLANE + off, lb + c       * WAVE_PX + lane * 4);
            stage16(tbase + c * HW_PLANE + off, lb + (3 + c) * WAVE_PX + lane * 4);
        }
    };

    stage(0, lbuf[0]);

    float lo = 0.0f, hi = 0.0f;
    #pragma unroll
    for (int s = 0; s < SUBTILES; ++s) {
        float* cur = lbuf[s & 1];
        if (s + 1 < SUBTILES) {
            stage(s + 1, lbuf[(s + 1) & 1]);
            // 6 newer DMAs outstanding; wait until only those remain ->
            // current buffer's 6 DMAs have landed. No barrier: tile is wave-private.
            asm volatile("s_waitcnt vmcnt(6)" ::: "memory");
        } else {
            asm volatile("s_waitcnt vmcnt(0)" ::: "memory");
        }
        const float* q = cur + lane * 4;
        float4 pr = *(const float4*)(q + 0 * WAVE_PX);
        float4 pg = *(const float4*)(q + 1 * WAVE_PX);
        float4 pb = *(const float4*)(q + 2 * WAVE_PX);
        float4 tr = *(const float4*)(q + 3 * WAVE_PX);
        float4 tg = *(const float4*)(q + 4 * WAVE_PX);
        float4 tb = *(const float4*)(q + 5 * WAVE_PX);
        acc_diff(hue1(pr.x, pg.x, pb.x), hue1(tr.x, tg.x, tb.x), lo, hi);
        acc_diff(hue1(pr.y, pg.y, pb.y), hue1(tr.y, tg.y, tb.y), lo, hi);
        acc_diff(hue1(pr.z, pg.z, pb.z), hue1(tr.z, tg.z, tb.z), lo, hi);
        acc_diff(hue1(pr.w, pg.w, pb.w), hue1(tr.w, tg.w, tb.w), lo, hi);
    }

    // wave (64-lane) shuffle reduction, then tiny block reduction
    for (int off = 32; off > 0; off >>= 1) {
        lo += __shfl_down(lo, off, 64);
        hi += __shfl_down(hi, off, 64);
    }
    __shared__ float slo[4], shi[4];
    if (lane == 0) { slo[wave] = lo; shi[wave] = hi; }
    __syncthreads();
    if (threadIdx.x == 0) {
        partial[blockIdx.x] =
            make_float2(slo[0] + slo[1] + slo[2] + slo[3],
                        shi[0] + shi[1] + shi[2] + shi[3]);
    }
}

__global__ void __launch_bounds__(256)
hsv_final(const float2* __restrict__ partial, float* __restrict__ out, int nblocks) {
    float lo = 0.0f, hi = 0.0f;
    for (int i = threadIdx.x; i < nblocks; i += blockDim.x) {
        float2 p = partial[i];
        lo += p.x; hi += p.y;
    }
    for (int off = 32; off > 0; off >>= 1) {
        lo += __shfl_down(lo, off, 64);
        hi += __shfl_down(hi, off, 64);
    }
    __shared__ float slo[4], shi[4];
    int lane = threadIdx.x & 63;
    int wave = threadIdx.x >> 6;
    if (lane == 0) { slo[wave] = lo; shi[wave] = hi; }
    __syncthreads();
    if (threadIdx.x == 0) {
        float L = slo[0] + slo[1] + slo[2] + slo[3];
        float H = shi[0] + shi[1] + shi[2] + shi[3];
        out[0] = (L + H) * (1.0f / (float)NPIX);
    }
}

extern "C" void kernel_launch(void* const* d_in, const int* in_sizes, int n_in,
                              void* d_out, int out_size, void* d_ws, size_t ws_size,
                              hipStream_t stream) {
    const float* pred = (const float*)d_in[0];
    const float* targ = (const float*)d_in[1];
    float*  out     = (float*)d_out;
    float2* partial = (float2*)d_ws;   // NBLOCKS * 8 B = 16 KiB scratch

    hsv_partial<<<NBLOCKS, 256, 0, stream>>>(pred, targ, partial);
    hsv_final<<<1, 256, 0, stream>>>(partial, out, NBLOCKS);
}

// Round 6
// 202.910 us; speedup vs baseline: 1.0810x; 1.0810x over previous
//
#include <hip/hip_runtime.h>

// Problem constants: (B, C, H, W) = (32, 3, 512, 512), fp32.
#define HW_PLANE (512 * 512)          // 262144, pow2 -> shift 18
#define NPIX     (32 * HW_PLANE)      // 8,388,608 pixels total
#define NBLOCKS  1024                 // R1's best-measured grid

// Native clang vector (NOT HIP_vector_type struct) — required by the builtin.
typedef float vfloat4 __attribute__((ext_vector_type(4)));

// Non-temporal 16B load: no-allocate/last-use cache bits — the variable under test.
__device__ __forceinline__ vfloat4 ldnt(const float* p) {
    return __builtin_nontemporal_load((const vfloat4*)p);
}

// Hue matching the jnp reference; rcp instead of IEEE divide (~1 ulp, threshold 4e-3).
__device__ __forceinline__ float hue1(float r, float g, float b) {
    float maxc  = fmaxf(r, fmaxf(g, b));
    float minc  = fminf(r, fminf(g, b));
    float delta = maxc - minc;
    float safe  = (delta == 0.0f) ? 1.0f : delta;
    float rs    = __builtin_amdgcn_rcpf(safe);
    float hr = (g - b) * rs;
    float hg = 2.0f + (b - r) * rs;
    float hb = 4.0f + (r - g) * rs;
    float h  = (maxc == r) ? hr : ((maxc == g) ? hg : hb);
    h = h * (1.0f / 6.0f);
    h = h - floorf(h);                 // Python % 1.0
    return (delta == 0.0f) ? 0.0f : h;
}

__device__ __forceinline__ void acc_diff(float hp, float ht, float& lo, float& hi) {
    float d = fabsf(hp - ht);
    if (d < 0.5f)      lo += d;        // d == 0.5 contributes to neither term
    else if (d > 0.5f) hi += d - 0.5f;
}

__global__ void __launch_bounds__(256)
hsv_partial(const float* __restrict__ pred, const float* __restrict__ targ,
            float2* __restrict__ partial) {
    const int tid    = blockIdx.x * blockDim.x + threadIdx.x;
    const int stride = gridDim.x * blockDim.x;
    const int N4     = NPIX / 4;       // one float4 (4 pixels) per iteration

    float lo = 0.0f, hi = 0.0f;
    #pragma unroll 2
    for (int i = tid; i < N4; i += stride) {
        int p    = i << 2;             // pixel index
        int bimg = p >> 18;            // p / HW_PLANE
        int pix  = p & (HW_PLANE - 1); // p % HW_PLANE
        int base = bimg * (3 * HW_PLANE) + pix;

        vfloat4 pr = ldnt(pred + base);
        vfloat4 pg = ldnt(pred + base + HW_PLANE);
        vfloat4 pb = ldnt(pred + base + 2 * HW_PLANE);
        vfloat4 tr = ldnt(targ + base);
        vfloat4 tg = ldnt(targ + base + HW_PLANE);
        vfloat4 tb = ldnt(targ + base + 2 * HW_PLANE);

        acc_diff(hue1(pr.x, pg.x, pb.x), hue1(tr.x, tg.x, tb.x), lo, hi);
        acc_diff(hue1(pr.y, pg.y, pb.y), hue1(tr.y, tg.y, tb.y), lo, hi);
        acc_diff(hue1(pr.z, pg.z, pb.z), hue1(tr.z, tg.z, tb.z), lo, hi);
        acc_diff(hue1(pr.w, pg.w, pb.w), hue1(tr.w, tg.w, tb.w), lo, hi);
    }

    // wave (64-lane) shuffle reduction
    for (int off = 32; off > 0; off >>= 1) {
        lo += __shfl_down(lo, off, 64);
        hi += __shfl_down(hi, off, 64);
    }
    __shared__ float slo[4], shi[4];   // 256 threads = 4 waves
    int lane = threadIdx.x & 63;
    int wave = threadIdx.x >> 6;
    if (lane == 0) { slo[wave] = lo; shi[wave] = hi; }
    __syncthreads();
    if (threadIdx.x == 0) {
        partial[blockIdx.x] =
            make_float2(slo[0] + slo[1] + slo[2] + slo[3],
                        shi[0] + shi[1] + shi[2] + shi[3]);
    }
}

__global__ void __launch_bounds__(256)
hsv_final(const float2* __restrict__ partial, float* __restrict__ out, int nblocks) {
    float lo = 0.0f, hi = 0.0f;
    for (int i = threadIdx.x; i < nblocks; i += blockDim.x) {
        float2 p = partial[i];
        lo += p.x; hi += p.y;
    }
    for (int off = 32; off > 0; off >>= 1) {
        lo += __shfl_down(lo, off, 64);
        hi += __shfl_down(hi, off, 64);
    }
    __shared__ float slo[4], shi[4];
    int lane = threadIdx.x & 63;
    int wave = threadIdx.x >> 6;
    if (lane == 0) { slo[wave] = lo; shi[wave] = hi; }
    __syncthreads();
    if (threadIdx.x == 0) {
        float L = slo[0] + slo[1] + slo[2] + slo[3];
        float H = shi[0] + shi[1] + shi[2] + shi[3];
        out[0] = (L + H) * (1.0f / (float)NPIX);
    }
}

extern "C" void kernel_launch(void* const* d_in, const int* in_sizes, int n_in,
                              void* d_out, int out_size, void* d_ws, size_t ws_size,
                              hipStream_t stream) {
    const float* pred = (const float*)d_in[0];
    const float* targ = (const float*)d_in[1];
    float*  out     = (float*)d_out;
    float2* partial = (float2*)d_ws;   // NBLOCKS * 8 B = 8 KiB scratch

    hsv_partial<<<NBLOCKS, 256, 0, stream>>>(pred, targ, partial);
    hsv_final<<<1, 256, 0, stream>>>(partial, out, NBLOCKS);
}

// Round 7
// 201.557 us; speedup vs baseline: 1.0883x; 1.0067x over previous
//
#include <hip/hip_runtime.h>

// Problem constants: (B, C, H, W) = (32, 3, 512, 512), fp32.
#define HW_PLANE (512 * 512)          // 262144, pow2 -> shift 18
#define NPIX     (32 * HW_PLANE)      // 8,388,608 pixels total
#define NBLOCKS  2048                 // 8 blocks/CU -> 32 waves/CU (single variable vs R6)

// Native clang vector (NOT HIP_vector_type struct) — required by the builtin.
typedef float vfloat4 __attribute__((ext_vector_type(4)));

// Non-temporal 16B load: no-allocate/last-use cache bits (R6's verified win).
__device__ __forceinline__ vfloat4 ldnt(const float* p) {
    return __builtin_nontemporal_load((const vfloat4*)p);
}

// Hue matching the jnp reference; rcp instead of IEEE divide (~1 ulp, threshold 4e-3).
__device__ __forceinline__ float hue1(float r, float g, float b) {
    float maxc  = fmaxf(r, fmaxf(g, b));
    float minc  = fminf(r, fminf(g, b));
    float delta = maxc - minc;
    float safe  = (delta == 0.0f) ? 1.0f : delta;
    float rs    = __builtin_amdgcn_rcpf(safe);
    float hr = (g - b) * rs;
    float hg = 2.0f + (b - r) * rs;
    float hb = 4.0f + (r - g) * rs;
    float h  = (maxc == r) ? hr : ((maxc == g) ? hg : hb);
    h = h * (1.0f / 6.0f);
    h = h - floorf(h);                 // Python % 1.0
    return (delta == 0.0f) ? 0.0f : h;
}

__device__ __forceinline__ void acc_diff(float hp, float ht, float& lo, float& hi) {
    float d = fabsf(hp - ht);
    if (d < 0.5f)      lo += d;        // d == 0.5 contributes to neither term
    else if (d > 0.5f) hi += d - 0.5f;
}

__global__ void __launch_bounds__(256)
hsv_partial(const float* __restrict__ pred, const float* __restrict__ targ,
            float2* __restrict__ partial) {
    const int tid    = blockIdx.x * blockDim.x + threadIdx.x;
    const int stride = gridDim.x * blockDim.x;
    const int N4     = NPIX / 4;       // one float4 (4 pixels) per iteration

    float lo = 0.0f, hi = 0.0f;
    #pragma unroll 2
    for (int i = tid; i < N4; i += stride) {
        int p    = i << 2;             // pixel index
        int bimg = p >> 18;            // p / HW_PLANE
        int pix  = p & (HW_PLANE - 1); // p % HW_PLANE
        int base = bimg * (3 * HW_PLANE) + pix;

        vfloat4 pr = ldnt(pred + base);
        vfloat4 pg = ldnt(pred + base + HW_PLANE);
        vfloat4 pb = ldnt(pred + base + 2 * HW_PLANE);
        vfloat4 tr = ldnt(targ + base);
        vfloat4 tg = ldnt(targ + base + HW_PLANE);
        vfloat4 tb = ldnt(targ + base + 2 * HW_PLANE);

        acc_diff(hue1(pr.x, pg.x, pb.x), hue1(tr.x, tg.x, tb.x), lo, hi);
        acc_diff(hue1(pr.y, pg.y, pb.y), hue1(tr.y, tg.y, tb.y), lo, hi);
        acc_diff(hue1(pr.z, pg.z, pb.z), hue1(tr.z, tg.z, tb.z), lo, hi);
        acc_diff(hue1(pr.w, pg.w, pb.w), hue1(tr.w, tg.w, tb.w), lo, hi);
    }

    // wave (64-lane) shuffle reduction
    for (int off = 32; off > 0; off >>= 1) {
        lo += __shfl_down(lo, off, 64);
        hi += __shfl_down(hi, off, 64);
    }
    __shared__ float slo[4], shi[4];   // 256 threads = 4 waves
    int lane = threadIdx.x & 63;
    int wave = threadIdx.x >> 6;
    if (lane == 0) { slo[wave] = lo; shi[wave] = hi; }
    __syncthreads();
    if (threadIdx.x == 0) {
        partial[blockIdx.x] =
            make_float2(slo[0] + slo[1] + slo[2] + slo[3],
                        shi[0] + shi[1] + shi[2] + shi[3]);
    }
}

__global__ void __launch_bounds__(256)
hsv_final(const float2* __restrict__ partial, float* __restrict__ out, int nblocks) {
    float lo = 0.0f, hi = 0.0f;
    for (int i = threadIdx.x; i < nblocks; i += blockDim.x) {
        float2 p = partial[i];
        lo += p.x; hi += p.y;
    }
    for (int off = 32; off > 0; off >>= 1) {
        lo += __shfl_down(lo, off, 64);
        hi += __shfl_down(hi, off, 64);
    }
    __shared__ float slo[4], shi[4];
    int lane = threadIdx.x & 63;
    int wave = threadIdx.x >> 6;
    if (lane == 0) { slo[wave] = lo; shi[wave] = hi; }
    __syncthreads();
    if (threadIdx.x == 0) {
        float L = slo[0] + slo[1] + slo[2] + slo[3];
        float H = shi[0] + shi[1] + shi[2] + shi[3];
        out[0] = (L + H) * (1.0f / (float)NPIX);
    }
}

extern "C" void kernel_launch(void* const* d_in, const int* in_sizes, int n_in,
                              void* d_out, int out_size, void* d_ws, size_t ws_size,
                              hipStream_t stream) {
    const float* pred = (const float*)d_in[0];
    const float* targ = (const float*)d_in[1];
    float*  out     = (float*)d_out;
    float2* partial = (float2*)d_ws;   // NBLOCKS * 8 B = 16 KiB scratch

    hsv_partial<<<NBLOCKS, 256, 0, stream>>>(pred, targ, partial);
    hsv_final<<<1, 256, 0, stream>>>(partial, out, NBLOCKS);
}